// Round 9
// baseline (48.133 us; speedup 1.0000x reference)
//
#include <hip/hip_runtime.h>

// PAB3D on MI355X (gfx950).  B=2, C=P=64, H=W=D=16, N=4096.
// R9: pass2 rebuilt with swapped S (mfma(top,cen) -> P^T lane-local) + free
// m->k permutation sigma so PV A-frags are assembled IN REGISTERS via
// v_cvt_pk_bf16_f32 (no pT LDS round-trip, no cross-lane ops); bot B-frags
// become paired ds_read_b64 at sigma^-1 offsets. xt1 vectorized (bf16x8).
// prep/convA/convOut unchanged from R8.

typedef __attribute__((ext_vector_type(8))) short bf16x8;
typedef __attribute__((ext_vector_type(4))) short short4v;
typedef __attribute__((ext_vector_type(4))) float f32x4;

#define DEVI static __device__ __forceinline__

DEVI f32x4 MFMA16(bf16x8 a, bf16x8 b, f32x4 c) {
  return __builtin_amdgcn_mfma_f32_16x16x32_bf16(a, b, c, 0, 0, 0);
}
DEVI f32x4 zero4() { return (f32x4){0.f, 0.f, 0.f, 0.f}; }

DEVI unsigned short f2bf(float f) {  // RNE float->bf16
  unsigned u = __float_as_uint(f);
  return (unsigned short)((u + 0x7fffu + ((u >> 16) & 1u)) >> 16);
}
DEVI float bf2f(unsigned short u) { return __uint_as_float((unsigned)u << 16); }
DEVI float fexp2(float x) { return __builtin_amdgcn_exp2f(x); }

DEVI unsigned cvtpk(float lo, float hi) {  // dst[15:0]=bf16(lo), dst[31:16]=bf16(hi), RNE
  unsigned d;
  asm("v_cvt_pk_bf16_f32 %0, %1, %2" : "=v"(d) : "v"(lo), "v"(hi));
  return d;
}
DEVI bf16x8 pack8(f32x4 a, f32x4 b) {  // e0..3 = a[0..3], e4..7 = b[0..3]
  union { unsigned u[4]; bf16x8 v; } r;
  r.u[0] = cvtpk(a[0], a[1]);
  r.u[1] = cvtpk(a[2], a[3]);
  r.u[2] = cvtpk(b[0], b[1]);
  r.u[3] = cvtpk(b[2], b[3]);
  return r.v;
}
DEVI bf16x8 cat44(short4v lo, short4v hi) {
  union { short4v s[2]; bf16x8 v; } c;
  c.s[0] = lo;
  c.s[1] = hi;
  return c.v;
}

// async global->LDS, 16B per lane; lds dest is wave-uniform base (HW adds lane*16)
DEVI void gll16(const unsigned short* g, unsigned short* l) {
  __builtin_amdgcn_global_load_lds(
      (const __attribute__((address_space(1))) void*)g,
      (__attribute__((address_space(3))) void*)l, 16, 0, 0);
}

// ---------------- fused: weight prep/permute (bx<432) + x transpose (bx>=432) --------
__global__ void k_prep(const float* __restrict__ tw, const float* __restrict__ cw,
                       const float* __restrict__ bw, const float* __restrict__ ow,
                       const float* __restrict__ x,
                       unsigned short* __restrict__ wkTopF, unsigned short* __restrict__ wkCenF,
                       unsigned short* __restrict__ wkBotF, unsigned short* __restrict__ wkOutF,
                       unsigned short* __restrict__ xT, unsigned short* __restrict__ zbuf) {
  __shared__ float tile[64][65];
  int bx = blockIdx.x;
  int tid = threadIdx.x;
  if (bx == 0 && tid < 64) zbuf[tid] = 0;  // 128B zero region for OOB halo staging
  if (bx < 432) {
    int t = bx * 256 + tid;
    if (t < 4096) {  // 1x1 weights: t = co*64+ci
      int co = t >> 6, ci = t & 63;
      int cog = co >> 4, col = co & 15, kc = ci >> 5, kg = (ci & 31) >> 3, e = ci & 7;
      int dst = (((cog * 2 + kc) * 64) + col + 16 * kg) * 8 + e;
      wkTopF[dst] = f2bf(tw[t]);
      wkCenF[dst] = f2bf(cw[t]);
    }
    // 3x3x3 weights: src [co][ci][k27]
    int k = t % 27;
    int ci = (t / 27) & 63;
    int co = t / (27 * 64);
    int cog = co >> 4, col = co & 15, kc = ci >> 5, kg = (ci & 31) >> 3, e = ci & 7;
    int dst = ((((cog * 27 + k) * 2 + kc) * 64) + col + 16 * kg) * 8 + e;
    wkBotF[dst] = f2bf(bw[t]);
    wkOutF[dst] = f2bf(ow[t]);
    return;
  }
  int bx2 = bx - 432;
  int b = bx2 >> 6;
  int n0 = (bx2 & 63) << 6;
  {
    int nl = tid & 63, cq = tid >> 6;
    const float* xb = x + (size_t)b * 262144;
#pragma unroll
    for (int j = 0; j < 16; j++) {
      int c = cq * 16 + j;
      tile[c][nl] = xb[(size_t)c * 4096 + n0 + nl];
    }
  }
  __syncthreads();
  {
    int n = tid >> 2, c0 = (tid & 3) << 4;
    bf16x8 o0, o1;
#pragma unroll
    for (int j = 0; j < 8; j++) {
      o0[j] = (short)f2bf(tile[c0 + j][n]);
      o1[j] = (short)f2bf(tile[c0 + 8 + j][n]);
    }
    unsigned short* dst = xT + ((size_t)(b * 4096 + n0 + n)) * 64 + c0;
    *(bf16x8*)(dst) = o0;
    *(bf16x8*)(dst + 8) = o1;
  }
}

// ---------------- staged 27-tap conv body ----------------
template <int OMODE>  // 2: bf16 [co][n]; 1: f32 [co][n]
DEVI void conv3_body(int bx, int t,
                     const unsigned short* __restrict__ wkF,
                     const unsigned short* __restrict__ xTb,
                     const float* __restrict__ bias,
                     const unsigned short* __restrict__ zbuf,
                     float* __restrict__ outF, unsigned short* __restrict__ outH,
                     unsigned short* hl) {
  int ch = bx & 1, wp = (bx >> 1) & 7, h = (bx >> 4) & 15, b = bx >> 8;
  int lane = t & 63, w = t >> 6;
  int col = lane & 15, kg = lane >> 4;
  const unsigned short* xb = xTb + (size_t)b * 262144;
  int row8 = lane >> 3, blk = lane & 7;
#pragma unroll
  for (int q = 0; q < 6; q++) {
    int vi0 = w * 48 + q * 8;
    int vi = vi0 + row8;
    int dhv = vi >> 6, wv = (vi >> 4) & 3, dv = vi & 15;
    int hh = h + dhv - 1, ww = wp * 2 + wv - 1;
    bool val = ((unsigned)hh < 16u) & ((unsigned)ww < 16u);
    int sw = blk ^ (vi & 7);
    const unsigned short* src =
        val ? (xb + ((size_t)((hh * 256 + ww * 16 + dv)) << 6) + sw * 8) : (zbuf + blk * 8);
    gll16(src, hl + vi0 * 64);
  }
  __syncthreads();
  int wi = w >> 1;
  int cg = ch * 2 + (w & 1);
  const char* hlb = (const char*)hl;
  f32x4 acc0 = zero4(), acc1 = zero4();
#pragma unroll
  for (int k = 0; k < 27; k++) {
    const int dh = k / 9;
    const int dw = (k / 3) % 3;
    const int dz = k % 3 - 1;
    int dsum = col + dz;
    bool vd = (unsigned)dsum < 16u;
    int dcl = vd ? dsum : col;
    int sv = dh * 64 + (wi + dw) * 16 + dcl;
    const unsigned short* wfk = wkF + (((size_t)(cg * 27 + k)) << 10) + lane * 8;
#pragma unroll
    for (int kc = 0; kc < 2; kc++) {
      bf16x8 av = *(const bf16x8*)(wfk + (kc << 9));
      int g = (kc * 4 + kg) ^ (sv & 7);
      bf16x8 bv = *(const bf16x8*)(hlb + sv * 128 + g * 16);
      if (!vd) bv = (bf16x8){0, 0, 0, 0, 0, 0, 0, 0};
      if (kc == 0) acc0 = MFMA16(av, bv, acc0);
      else acc1 = MFMA16(av, bv, acc1);
    }
  }
  int n0c = h * 256 + (wp * 2 + wi) * 16 + col;
#pragma unroll
  for (int r = 0; r < 4; r++) {
    int co = ch * 32 + (w & 1) * 16 + kg * 4 + r;
    float v = acc0[r] + acc1[r] + bias[co];
    if (OMODE == 2)
      outH[(size_t)(b * 64 + co) * 4096 + n0c] = f2bf(v);
    else
      outF[(size_t)(b * 64 + co) * 4096 + n0c] = v;
  }
}

// ---------------- fused: top+center 1x1x1 (bx<512) + bottom 3x3x3 staged (bx>=512) ----
__global__ __launch_bounds__(256, 2) void k_convA(
    const unsigned short* __restrict__ wkTf, const unsigned short* __restrict__ wkCf,
    const unsigned short* __restrict__ wkBf, const unsigned short* __restrict__ xTb,
    const float* __restrict__ tbias, const float* __restrict__ cbias,
    const float* __restrict__ bbias, const unsigned short* __restrict__ zbuf,
    unsigned short* __restrict__ topT, unsigned short* __restrict__ cenT,
    unsigned short* __restrict__ botS) {
  __shared__ __align__(16) unsigned short hl[192 * 64];
  int bx0 = blockIdx.x;
  int t = threadIdx.x;
  if (bx0 >= 512) {
    conv3_body<2>(bx0 - 512, t, wkBf, xTb, bbias, zbuf, nullptr, botS, hl);
    return;
  }
  int lane = t & 63, wid = t >> 6;
  int col = lane & 15, kg = lane >> 4;
  int bx = bx0;
  int b = bx >> 8;
  int rest = bx & 255;
  int nt = rest >> 1, ch = rest & 1;
  int cg = ch * 2 + (wid >> 1);
  int co0 = ch * 32 + (wid >> 1) * 16;
  int n0c = nt * 32 + (wid & 1) * 16 + col;
  const unsigned short* xb = xTb + (size_t)b * 262144;
  f32x4 aT0 = zero4(), aT1 = zero4(), aC0 = zero4(), aC1 = zero4();
#pragma unroll
  for (int kc = 0; kc < 2; kc++) {
    bf16x8 bv = *(const bf16x8*)(xb + (size_t)n0c * 64 + kc * 32 + kg * 8);
    bf16x8 avT = *(const bf16x8*)(wkTf + (((size_t)cg * 2 + kc) * 64 + lane) * 8);
    bf16x8 avC = *(const bf16x8*)(wkCf + (((size_t)cg * 2 + kc) * 64 + lane) * 8);
    if (kc == 0) {
      aT0 = MFMA16(avT, bv, aT0);
      aC0 = MFMA16(avC, bv, aC0);
    } else {
      aT1 = MFMA16(avT, bv, aT1);
      aC1 = MFMA16(avC, bv, aC1);
    }
  }
  const float LOG2E = 1.4426950408889634f;
  short4v sT, sC;
#pragma unroll
  for (int r = 0; r < 4; r++) {
    float bvT = tbias[co0 + kg * 4 + r];
    float bvC = cbias[co0 + kg * 4 + r];
    sT[r] = (short)f2bf(aT0[r] + aT1[r] + bvT);
    sC[r] = (short)f2bf((aC0[r] + aC1[r] + bvC) * LOG2E);  // fold log2e for exp2
  }
  size_t o = (size_t)(b * 4096 + n0c) * 64 + co0 + kg * 4;
  *(short4v*)(topT + o) = sT;
  *(short4v*)(cenT + o) = sC;
}

// ---------------- out 3x3x3 conv (staged) -> f32 d_out ----------------
__global__ __launch_bounds__(256, 2) void k_convOut(
    const unsigned short* __restrict__ wkOf, const unsigned short* __restrict__ xTb,
    const float* __restrict__ bias, const unsigned short* __restrict__ zbuf,
    float* __restrict__ outF) {
  __shared__ __align__(16) unsigned short hl[192 * 64];
  conv3_body<1>(blockIdx.x, threadIdx.x, wkOf, xTb, bias, zbuf, outF, nullptr, hl);
}

// ---------------- pass 2: swapped-S, in-register P, O-partials + Z-partials ---------
// grid = B x 32 ntpairs(128 rows) x 8 mchunks(512 m); wave w owns rows {+w*16, +64+w*16}.
// S^T = mfma(top, cen): lane holds P[n=col][m=mt*16+kg*4+r].
// sigma(m): frag(kc) e = (mt&1)*4+r for mt in {2kc, 2kc+1}; bot B-frag reads the
// matching two 4-m groups as ds_read_b64 pairs (same sigma -> contraction correct).
__global__ __launch_bounds__(256, 2) void k_pass2(
    const unsigned short* __restrict__ cenT, const unsigned short* __restrict__ topT,
    const unsigned short* __restrict__ botS,
    unsigned short* __restrict__ part, float* __restrict__ Zpart) {
  __shared__ __align__(16) unsigned short topS[2][4096];
  __shared__ __align__(16) unsigned short botL[2][4096];
  __shared__ float zred[4];
  int bx = blockIdx.x;
  int b = bx >> 8;
  int ntp = (bx >> 3) & 31;
  int mc = bx & 7;
  int t = threadIdx.x;
  int lane = t & 63, w = t >> 6;
  int col = lane & 15, kg = lane >> 4;
  const unsigned short* cb = cenT + (size_t)b * 262144;
  const unsigned short* tb = topT + (size_t)b * 262144;
  const unsigned short* bb = botS + (size_t)b * 262144;
  int nA = ntp * 128 + w * 16;
  int mcBase = mc * 512;
  int row8 = lane >> 3, blk = lane & 7;
  int sw = blk ^ (row8 & 7);

  // cen frags (B operand now; same bytes as before)
  bf16x8 aA0 = *(const bf16x8*)(cb + (size_t)(nA + col) * 64 + kg * 8);
  bf16x8 aA1 = *(const bf16x8*)(cb + (size_t)(nA + col) * 64 + 32 + kg * 8);
  bf16x8 aB0 = *(const bf16x8*)(cb + (size_t)(nA + 64 + col) * 64 + kg * 8);
  bf16x8 aB1 = *(const bf16x8*)(cb + (size_t)(nA + 64 + col) * 64 + 32 + kg * 8);

  // prologue stage j=0: waves 0,1 -> top; waves 2,3 -> bot
  if (w < 2) {
#pragma unroll
    for (int q = 0; q < 4; q++) {
      int s = w * 4 + q;
      gll16(tb + (size_t)(mcBase + s * 8 + row8) * 64 + sw * 8, &topS[0][s * 512]);
    }
  } else {
#pragma unroll
    for (int q = 0; q < 4; q++) {
      int s = (w - 2) * 4 + q;
      gll16(bb + (size_t)(s * 8 + row8) * 4096 + mcBase + sw * 8, &botL[0][s * 512]);
    }
  }
  __syncthreads();

  f32x4 accOA[4], accOB[4];
#pragma unroll
  for (int ct = 0; ct < 4; ct++) {
    accOA[ct] = zero4();
    accOB[ct] = zero4();
  }
  float zs = 0.f;
  int swc = (col & 7) << 3;
  // precomputed b64 read offsets (u16 units) for the sigma^-1 m-groups
  int bofs[2][2];
#pragma unroll
  for (int kc = 0; kc < 2; kc++) {
    bofs[kc][0] = (((kc * 4 + (kg >> 1)) ^ (col & 7)) << 3) + (kg & 1) * 4;      // m=kc*32+kg*4
    bofs[kc][1] = (((kc * 4 + 2 + (kg >> 1)) ^ (col & 7)) << 3) + (kg & 1) * 4;  // +16
  }

  for (int j = 0; j < 8; j++) {
    int cur = j & 1;
    if (j < 7) {
      int m0n = mcBase + (j + 1) * 64;
      if (w < 2) {
#pragma unroll
        for (int q = 0; q < 4; q++) {
          int s = w * 4 + q;
          gll16(tb + (size_t)(m0n + s * 8 + row8) * 64 + sw * 8, &topS[cur ^ 1][s * 512]);
        }
      } else {
#pragma unroll
        for (int q = 0; q < 4; q++) {
          int s = (w - 2) * 4 + q;
          gll16(bb + (size_t)(s * 8 + row8) * 4096 + m0n + sw * 8, &botL[cur ^ 1][s * 512]);
        }
      }
    }
    // S^T tiles: D[m-rows][n-cols]; lane holds P[n=col][m=mt*16+kg*4+r]
    f32x4 sA[4], sB[4];
#pragma unroll
    for (int mt = 0; mt < 4; mt++) {
      bf16x8 b0 = *(const bf16x8*)&topS[cur][(mt * 16 + col) * 64 + ((kg * 8) ^ swc)];
      bf16x8 b1 = *(const bf16x8*)&topS[cur][(mt * 16 + col) * 64 + ((32 + kg * 8) ^ swc)];
      sA[mt] = MFMA16(b1, aA1, MFMA16(b0, aA0, zero4()));
      sB[mt] = MFMA16(b1, aB1, MFMA16(b0, aB0, zero4()));
    }
    // P = exp2(S') in place + Z accumulate
#pragma unroll
    for (int mt = 0; mt < 4; mt++)
#pragma unroll
      for (int r = 0; r < 4; r++) {
        sA[mt][r] = fexp2(sA[mt][r]);
        sB[mt][r] = fexp2(sB[mt][r]);
        zs += sA[mt][r] + sB[mt][r];
      }
    // PV: A-frags packed in-register; B-frags = paired b64 reads (sigma^-1 groups)
#pragma unroll
    for (int kc = 0; kc < 2; kc++) {
      bf16x8 paA = pack8(sA[2 * kc], sA[2 * kc + 1]);
      bf16x8 paB = pack8(sB[2 * kc], sB[2 * kc + 1]);
#pragma unroll
      for (int ct = 0; ct < 4; ct++) {
        const unsigned short* brow = &botL[cur][(ct * 16 + col) * 64];
        short4v lo = *(const short4v*)(brow + bofs[kc][0]);
        short4v hi = *(const short4v*)(brow + bofs[kc][1]);
        bf16x8 bv = cat44(lo, hi);
        accOA[ct] = MFMA16(paA, bv, accOA[ct]);
        accOB[ct] = MFMA16(paB, bv, accOB[ct]);
      }
    }
    __syncthreads();
  }
  // raw bf16 partials: part[b][mc][n][c]  (invZ applied in k_xt1)
  unsigned short* po = part + (((size_t)(b * 8 + mc) * 4096 + nA) << 6);
#pragma unroll
  for (int ct = 0; ct < 4; ct++)
#pragma unroll
    for (int r = 0; r < 4; r++) {
      po[(kg * 4 + r) * 64 + ct * 16 + col] = f2bf(accOA[ct][r]);
      po[(64 + kg * 4 + r) * 64 + ct * 16 + col] = f2bf(accOB[ct][r]);
    }
  // Z partial: wave reduce + block reduce
#pragma unroll
  for (int off = 32; off; off >>= 1) zs += __shfl_xor(zs, off);
  if (lane == 0) zred[w] = zs;
  __syncthreads();
  if (t == 0) Zpart[b * 256 + ntp * 8 + mc] = zred[0] + zred[1] + zred[2] + zred[3];
}

// ---------------- yT = bf16(x + (sum_mc part) * invZ), vectorized -------------------
__global__ void k_xt1(const float* __restrict__ x, const unsigned short* __restrict__ part,
                      const float* __restrict__ Zpart, unsigned short* __restrict__ xT) {
  __shared__ float tile[64][65];
  __shared__ float zr[4];
  int bx = blockIdx.x;
  int b = bx >> 6;
  int n0 = (bx & 63) << 6;
  int t = threadIdx.x;
  float zv = Zpart[b * 256 + t];
#pragma unroll
  for (int off = 32; off; off >>= 1) zv += __shfl_xor(zv, off);
  if ((t & 63) == 0) zr[t >> 6] = zv;
  __syncthreads();
  float invZ = 1.0f / (zr[0] + zr[1] + zr[2] + zr[3]);
  {
    // thread handles (c = t>>2, nl16 = (t&3)*16): 16 consecutive nl
    int c = t >> 2, nl16 = (t & 3) << 4;
    int nt6 = n0 >> 6;
    float acc[16];
#pragma unroll
    for (int k = 0; k < 16; k++) acc[k] = 0.f;
#pragma unroll
    for (int mcq = 0; mcq < 8; mcq++) {
      const unsigned short* pp =
          part + (((size_t)(b * 8 + mcq) * 4096) + c * 64 + nt6) * 64 + nl16;
      bf16x8 v0 = *(const bf16x8*)pp;
      bf16x8 v1 = *(const bf16x8*)(pp + 8);
#pragma unroll
      for (int k = 0; k < 8; k++) {
        acc[k] += bf2f((unsigned short)v0[k]);
        acc[8 + k] += bf2f((unsigned short)v1[k]);
      }
    }
    const float* xb = x + (size_t)b * 262144 + (size_t)c * 4096 + n0 + nl16;
#pragma unroll
    for (int q = 0; q < 4; q++) {
      f32x4 xv = *(const f32x4*)(xb + q * 4);
#pragma unroll
      for (int k = 0; k < 4; k++) tile[c][nl16 + q * 4 + k] = xv[k] + acc[q * 4 + k] * invZ;
    }
  }
  __syncthreads();
  {
    int n = t >> 2, c0 = (t & 3) << 4;
    bf16x8 o0, o1;
#pragma unroll
    for (int j = 0; j < 8; j++) {
      o0[j] = (short)f2bf(tile[c0 + j][n]);
      o1[j] = (short)f2bf(tile[c0 + 8 + j][n]);
    }
    unsigned short* dst = xT + ((size_t)(b * 4096 + n0 + n)) * 64 + c0;
    *(bf16x8*)(dst) = o0;
    *(bf16x8*)(dst + 8) = o1;
  }
}

// ---------------- host ----------------
extern "C" void kernel_launch(void* const* d_in, const int* in_sizes, int n_in,
                              void* d_out, int out_size, void* d_ws, size_t ws_size,
                              hipStream_t stream) {
  const float* x = (const float*)d_in[0];
  const float* tw = (const float*)d_in[1];
  const float* tb = (const float*)d_in[2];
  const float* cw = (const float*)d_in[3];
  const float* cbb = (const float*)d_in[4];
  const float* bw = (const float*)d_in[5];
  const float* bb = (const float*)d_in[6];
  const float* ow = (const float*)d_in[7];
  const float* ob = (const float*)d_in[8];
  float* out = (float*)d_out;
  char* ws = (char*)d_ws;

  unsigned short* wkTopF = (unsigned short*)(ws + 0);       // 8 KB (frag layout)
  unsigned short* wkCenF = (unsigned short*)(ws + 8192);    // 8 KB
  unsigned short* wkBotF = (unsigned short*)(ws + 16384);   // 216 KB
  unsigned short* wkOutF = (unsigned short*)(ws + 237568);  // 216 KB
  unsigned short* xT = (unsigned short*)(ws + 458752);      // 1 MB
  unsigned short* topT = (unsigned short*)(ws + 1507328);   // 1 MB
  unsigned short* cenT = (unsigned short*)(ws + 2555904);   // 1 MB
  unsigned short* botS = (unsigned short*)(ws + 3604480);   // 1 MB
  unsigned short* yT = (unsigned short*)(ws + 4653056);     // 1 MB
  unsigned short* part = (unsigned short*)(ws + 5701632);   // 8 MB bf16 [2][8][4096][64]
  float* Zpart = (float*)(ws + 14090240);                   // 2 KB
  unsigned short* zbuf = (unsigned short*)(ws + 14092288);  // 128 B zeros

  k_prep<<<560, 256, 0, stream>>>(tw, cw, bw, ow, x, wkTopF, wkCenF, wkBotF, wkOutF, xT, zbuf);
  k_convA<<<1024, 256, 0, stream>>>(wkTopF, wkCenF, wkBotF, xT, tb, cbb, bb, zbuf, topT, cenT, botS);
  k_pass2<<<512, 256, 0, stream>>>(cenT, topT, botS, part, Zpart);
  k_xt1<<<128, 256, 0, stream>>>(x, part, Zpart, yT);
  k_convOut<<<512, 256, 0, stream>>>(wkOutF, yT, ob, zbuf, out);
}

// Round 10
// 43.946 us; speedup vs baseline: 1.0953x; 1.0953x over previous
//
#include <hip/hip_runtime.h>

// PAB3D on MI355X (gfx950).  B=2, C=P=64, H=W=D=16, N=4096.
// R10 = R9 with the PV B-side fixed: the sigma^-1 m-permutation is applied at
// botS WRITE time (free bit-shuffle in the conv epilogue scalar stores), so the
// PV B-frag is a single swizzled 16B LDS read again (R8's conflict-free pattern)
// while P stays in-register via v_cvt_pk_bf16_f32 (no pT LDS round-trip).
// R9's paired b64 reads caused 1M bank conflicts + VGPR 128 -> reverted.

typedef __attribute__((ext_vector_type(8))) short bf16x8;
typedef __attribute__((ext_vector_type(4))) short short4v;
typedef __attribute__((ext_vector_type(4))) float f32x4;

#define DEVI static __device__ __forceinline__

DEVI f32x4 MFMA16(bf16x8 a, bf16x8 b, f32x4 c) {
  return __builtin_amdgcn_mfma_f32_16x16x32_bf16(a, b, c, 0, 0, 0);
}
DEVI f32x4 zero4() { return (f32x4){0.f, 0.f, 0.f, 0.f}; }

DEVI unsigned short f2bf(float f) {  // RNE float->bf16
  unsigned u = __float_as_uint(f);
  return (unsigned short)((u + 0x7fffu + ((u >> 16) & 1u)) >> 16);
}
DEVI float bf2f(unsigned short u) { return __uint_as_float((unsigned)u << 16); }
DEVI float fexp2(float x) { return __builtin_amdgcn_exp2f(x); }

DEVI unsigned cvtpk(float lo, float hi) {  // dst[15:0]=bf16(lo), dst[31:16]=bf16(hi), RNE
  unsigned d;
  asm("v_cvt_pk_bf16_f32 %0, %1, %2" : "=v"(d) : "v"(lo), "v"(hi));
  return d;
}
DEVI bf16x8 pack8(f32x4 a, f32x4 b) {  // e0..3 = a[0..3], e4..7 = b[0..3]
  union { unsigned u[4]; bf16x8 v; } r;
  r.u[0] = cvtpk(a[0], a[1]);
  r.u[1] = cvtpk(a[2], a[3]);
  r.u[2] = cvtpk(b[0], b[1]);
  r.u[3] = cvtpk(b[2], b[3]);
  return r.v;
}

// async global->LDS, 16B per lane; lds dest is wave-uniform base (HW adds lane*16)
DEVI void gll16(const unsigned short* g, unsigned short* l) {
  __builtin_amdgcn_global_load_lds(
      (const __attribute__((address_space(1))) void*)g,
      (__attribute__((address_space(3))) void*)l, 16, 0, 0);
}

// sigma storage permutation within each 64-chunk of m:
// p[5]=n[5], p[4:3]=n[3:2], p[2]=n[4], p[1:0]=n[1:0]
DEVI int permM(int n) {
  return (n & ~63) | (n & 32) | ((n & 12) << 1) | ((n & 16) >> 2) | (n & 3);
}

// ---------------- fused: weight prep/permute (bx<432) + x transpose (bx>=432) --------
__global__ void k_prep(const float* __restrict__ tw, const float* __restrict__ cw,
                       const float* __restrict__ bw, const float* __restrict__ ow,
                       const float* __restrict__ x,
                       unsigned short* __restrict__ wkTopF, unsigned short* __restrict__ wkCenF,
                       unsigned short* __restrict__ wkBotF, unsigned short* __restrict__ wkOutF,
                       unsigned short* __restrict__ xT, unsigned short* __restrict__ zbuf) {
  __shared__ float tile[64][65];
  int bx = blockIdx.x;
  int tid = threadIdx.x;
  if (bx == 0 && tid < 64) zbuf[tid] = 0;  // 128B zero region for OOB halo staging
  if (bx < 432) {
    int t = bx * 256 + tid;
    if (t < 4096) {  // 1x1 weights: t = co*64+ci
      int co = t >> 6, ci = t & 63;
      int cog = co >> 4, col = co & 15, kc = ci >> 5, kg = (ci & 31) >> 3, e = ci & 7;
      int dst = (((cog * 2 + kc) * 64) + col + 16 * kg) * 8 + e;
      wkTopF[dst] = f2bf(tw[t]);
      wkCenF[dst] = f2bf(cw[t]);
    }
    // 3x3x3 weights: src [co][ci][k27]
    int k = t % 27;
    int ci = (t / 27) & 63;
    int co = t / (27 * 64);
    int cog = co >> 4, col = co & 15, kc = ci >> 5, kg = (ci & 31) >> 3, e = ci & 7;
    int dst = ((((cog * 27 + k) * 2 + kc) * 64) + col + 16 * kg) * 8 + e;
    wkBotF[dst] = f2bf(bw[t]);
    wkOutF[dst] = f2bf(ow[t]);
    return;
  }
  int bx2 = bx - 432;
  int b = bx2 >> 6;
  int n0 = (bx2 & 63) << 6;
  {
    int nl = tid & 63, cq = tid >> 6;
    const float* xb = x + (size_t)b * 262144;
#pragma unroll
    for (int j = 0; j < 16; j++) {
      int c = cq * 16 + j;
      tile[c][nl] = xb[(size_t)c * 4096 + n0 + nl];
    }
  }
  __syncthreads();
  {
    int n = tid >> 2, c0 = (tid & 3) << 4;
    bf16x8 o0, o1;
#pragma unroll
    for (int j = 0; j < 8; j++) {
      o0[j] = (short)f2bf(tile[c0 + j][n]);
      o1[j] = (short)f2bf(tile[c0 + 8 + j][n]);
    }
    unsigned short* dst = xT + ((size_t)(b * 4096 + n0 + n)) * 64 + c0;
    *(bf16x8*)(dst) = o0;
    *(bf16x8*)(dst + 8) = o1;
  }
}

// ---------------- staged 27-tap conv body ----------------
template <int OMODE>  // 2: bf16 [co][permM(n)] (for pass2); 1: f32 [co][n]
DEVI void conv3_body(int bx, int t,
                     const unsigned short* __restrict__ wkF,
                     const unsigned short* __restrict__ xTb,
                     const float* __restrict__ bias,
                     const unsigned short* __restrict__ zbuf,
                     float* __restrict__ outF, unsigned short* __restrict__ outH,
                     unsigned short* hl) {
  int ch = bx & 1, wp = (bx >> 1) & 7, h = (bx >> 4) & 15, b = bx >> 8;
  int lane = t & 63, w = t >> 6;
  int col = lane & 15, kg = lane >> 4;
  const unsigned short* xb = xTb + (size_t)b * 262144;
  int row8 = lane >> 3, blk = lane & 7;
#pragma unroll
  for (int q = 0; q < 6; q++) {
    int vi0 = w * 48 + q * 8;
    int vi = vi0 + row8;
    int dhv = vi >> 6, wv = (vi >> 4) & 3, dv = vi & 15;
    int hh = h + dhv - 1, ww = wp * 2 + wv - 1;
    bool val = ((unsigned)hh < 16u) & ((unsigned)ww < 16u);
    int sw = blk ^ (vi & 7);
    const unsigned short* src =
        val ? (xb + ((size_t)((hh * 256 + ww * 16 + dv)) << 6) + sw * 8) : (zbuf + blk * 8);
    gll16(src, hl + vi0 * 64);
  }
  __syncthreads();
  int wi = w >> 1;
  int cg = ch * 2 + (w & 1);
  const char* hlb = (const char*)hl;
  f32x4 acc0 = zero4(), acc1 = zero4();
#pragma unroll
  for (int k = 0; k < 27; k++) {
    const int dh = k / 9;
    const int dw = (k / 3) % 3;
    const int dz = k % 3 - 1;
    int dsum = col + dz;
    bool vd = (unsigned)dsum < 16u;
    int dcl = vd ? dsum : col;
    int sv = dh * 64 + (wi + dw) * 16 + dcl;
    const unsigned short* wfk = wkF + (((size_t)(cg * 27 + k)) << 10) + lane * 8;
#pragma unroll
    for (int kc = 0; kc < 2; kc++) {
      bf16x8 av = *(const bf16x8*)(wfk + (kc << 9));
      int g = (kc * 4 + kg) ^ (sv & 7);
      bf16x8 bv = *(const bf16x8*)(hlb + sv * 128 + g * 16);
      if (!vd) bv = (bf16x8){0, 0, 0, 0, 0, 0, 0, 0};
      if (kc == 0) acc0 = MFMA16(av, bv, acc0);
      else acc1 = MFMA16(av, bv, acc1);
    }
  }
  int n0c = h * 256 + (wp * 2 + wi) * 16 + col;
  int nst = (OMODE == 2) ? permM(n0c) : n0c;  // sigma perm for pass2's PV B-frags
#pragma unroll
  for (int r = 0; r < 4; r++) {
    int co = ch * 32 + (w & 1) * 16 + kg * 4 + r;
    float v = acc0[r] + acc1[r] + bias[co];
    if (OMODE == 2)
      outH[(size_t)(b * 64 + co) * 4096 + nst] = f2bf(v);
    else
      outF[(size_t)(b * 64 + co) * 4096 + nst] = v;
  }
}

// ---------------- fused: top+center 1x1x1 (bx<512) + bottom 3x3x3 staged (bx>=512) ----
__global__ __launch_bounds__(256, 2) void k_convA(
    const unsigned short* __restrict__ wkTf, const unsigned short* __restrict__ wkCf,
    const unsigned short* __restrict__ wkBf, const unsigned short* __restrict__ xTb,
    const float* __restrict__ tbias, const float* __restrict__ cbias,
    const float* __restrict__ bbias, const unsigned short* __restrict__ zbuf,
    unsigned short* __restrict__ topT, unsigned short* __restrict__ cenT,
    unsigned short* __restrict__ botS) {
  __shared__ __align__(16) unsigned short hl[192 * 64];
  int bx0 = blockIdx.x;
  int t = threadIdx.x;
  if (bx0 >= 512) {
    conv3_body<2>(bx0 - 512, t, wkBf, xTb, bbias, zbuf, nullptr, botS, hl);
    return;
  }
  int lane = t & 63, wid = t >> 6;
  int col = lane & 15, kg = lane >> 4;
  int bx = bx0;
  int b = bx >> 8;
  int rest = bx & 255;
  int nt = rest >> 1, ch = rest & 1;
  int cg = ch * 2 + (wid >> 1);
  int co0 = ch * 32 + (wid >> 1) * 16;
  int n0c = nt * 32 + (wid & 1) * 16 + col;
  const unsigned short* xb = xTb + (size_t)b * 262144;
  f32x4 aT0 = zero4(), aT1 = zero4(), aC0 = zero4(), aC1 = zero4();
#pragma unroll
  for (int kc = 0; kc < 2; kc++) {
    bf16x8 bv = *(const bf16x8*)(xb + (size_t)n0c * 64 + kc * 32 + kg * 8);
    bf16x8 avT = *(const bf16x8*)(wkTf + (((size_t)cg * 2 + kc) * 64 + lane) * 8);
    bf16x8 avC = *(const bf16x8*)(wkCf + (((size_t)cg * 2 + kc) * 64 + lane) * 8);
    if (kc == 0) {
      aT0 = MFMA16(avT, bv, aT0);
      aC0 = MFMA16(avC, bv, aC0);
    } else {
      aT1 = MFMA16(avT, bv, aT1);
      aC1 = MFMA16(avC, bv, aC1);
    }
  }
  const float LOG2E = 1.4426950408889634f;
  short4v sT, sC;
#pragma unroll
  for (int r = 0; r < 4; r++) {
    float bvT = tbias[co0 + kg * 4 + r];
    float bvC = cbias[co0 + kg * 4 + r];
    sT[r] = (short)f2bf(aT0[r] + aT1[r] + bvT);
    sC[r] = (short)f2bf((aC0[r] + aC1[r] + bvC) * LOG2E);  // fold log2e for exp2
  }
  size_t o = (size_t)(b * 4096 + n0c) * 64 + co0 + kg * 4;
  *(short4v*)(topT + o) = sT;
  *(short4v*)(cenT + o) = sC;
}

// ---------------- out 3x3x3 conv (staged) -> f32 d_out ----------------
__global__ __launch_bounds__(256, 2) void k_convOut(
    const unsigned short* __restrict__ wkOf, const unsigned short* __restrict__ xTb,
    const float* __restrict__ bias, const unsigned short* __restrict__ zbuf,
    float* __restrict__ outF) {
  __shared__ __align__(16) unsigned short hl[192 * 64];
  conv3_body<1>(blockIdx.x, threadIdx.x, wkOf, xTb, bias, zbuf, outF, nullptr, hl);
}

// ---------------- pass 2: swapped-S, in-register P, O-partials + Z-partials ---------
// grid = B x 32 ntpairs(128 rows) x 8 mchunks(512 m); wave w owns rows {+w*16, +64+w*16}.
// S^T = mfma(top, cen): lane holds P[n=col][m=mt*16+kg*4+r].
// sigma(kc,kg,e) = 32kc + 16(e>>2) + 4kg + (e&3); A-frag = lane-local cvt_pk pack;
// botS is STORED sigma-permuted (permM in conv) so B-frag is one swizzled 16B read.
__global__ __launch_bounds__(256, 2) void k_pass2(
    const unsigned short* __restrict__ cenT, const unsigned short* __restrict__ topT,
    const unsigned short* __restrict__ botS,
    unsigned short* __restrict__ part, float* __restrict__ Zpart) {
  __shared__ __align__(16) unsigned short topS[2][4096];
  __shared__ __align__(16) unsigned short botL[2][4096];
  __shared__ float zred[4];
  int bx = blockIdx.x;
  int b = bx >> 8;
  int ntp = (bx >> 3) & 31;
  int mc = bx & 7;
  int t = threadIdx.x;
  int lane = t & 63, w = t >> 6;
  int col = lane & 15, kg = lane >> 4;
  const unsigned short* cb = cenT + (size_t)b * 262144;
  const unsigned short* tb = topT + (size_t)b * 262144;
  const unsigned short* bb = botS + (size_t)b * 262144;
  int nA = ntp * 128 + w * 16;
  int mcBase = mc * 512;
  int row8 = lane >> 3, blk = lane & 7;
  int sw = blk ^ (row8 & 7);

  bf16x8 aA0 = *(const bf16x8*)(cb + (size_t)(nA + col) * 64 + kg * 8);
  bf16x8 aA1 = *(const bf16x8*)(cb + (size_t)(nA + col) * 64 + 32 + kg * 8);
  bf16x8 aB0 = *(const bf16x8*)(cb + (size_t)(nA + 64 + col) * 64 + kg * 8);
  bf16x8 aB1 = *(const bf16x8*)(cb + (size_t)(nA + 64 + col) * 64 + 32 + kg * 8);

  // prologue stage j=0: waves 0,1 -> top; waves 2,3 -> bot (bot rows are perm-stored)
  if (w < 2) {
#pragma unroll
    for (int q = 0; q < 4; q++) {
      int s = w * 4 + q;
      gll16(tb + (size_t)(mcBase + s * 8 + row8) * 64 + sw * 8, &topS[0][s * 512]);
    }
  } else {
#pragma unroll
    for (int q = 0; q < 4; q++) {
      int s = (w - 2) * 4 + q;
      gll16(bb + (size_t)(s * 8 + row8) * 4096 + mcBase + sw * 8, &botL[0][s * 512]);
    }
  }
  __syncthreads();

  f32x4 accOA[4], accOB[4];
#pragma unroll
  for (int ct = 0; ct < 4; ct++) {
    accOA[ct] = zero4();
    accOB[ct] = zero4();
  }
  float zs = 0.f;
  int swc = (col & 7) << 3;

  for (int j = 0; j < 8; j++) {
    int cur = j & 1;
    if (j < 7) {
      int m0n = mcBase + (j + 1) * 64;
      if (w < 2) {
#pragma unroll
        for (int q = 0; q < 4; q++) {
          int s = w * 4 + q;
          gll16(tb + (size_t)(m0n + s * 8 + row8) * 64 + sw * 8, &topS[cur ^ 1][s * 512]);
        }
      } else {
#pragma unroll
        for (int q = 0; q < 4; q++) {
          int s = (w - 2) * 4 + q;
          gll16(bb + (size_t)(s * 8 + row8) * 4096 + m0n + sw * 8, &botL[cur ^ 1][s * 512]);
        }
      }
    }
    // S^T tiles: lane holds P[n=col][m=mt*16+kg*4+r]
    f32x4 sA[4], sB[4];
#pragma unroll
    for (int mt = 0; mt < 4; mt++) {
      bf16x8 b0 = *(const bf16x8*)&topS[cur][(mt * 16 + col) * 64 + ((kg * 8) ^ swc)];
      bf16x8 b1 = *(const bf16x8*)&topS[cur][(mt * 16 + col) * 64 + ((32 + kg * 8) ^ swc)];
      sA[mt] = MFMA16(b1, aA1, MFMA16(b0, aA0, zero4()));
      sB[mt] = MFMA16(b1, aB1, MFMA16(b0, aB0, zero4()));
    }
    // P = exp2(S') in place + Z accumulate
#pragma unroll
    for (int mt = 0; mt < 4; mt++)
#pragma unroll
      for (int r = 0; r < 4; r++) {
        sA[mt][r] = fexp2(sA[mt][r]);
        sB[mt][r] = fexp2(sB[mt][r]);
        zs += sA[mt][r] + sB[mt][r];
      }
    // PV: A-frags packed in-register; B-frag = one swizzled 16B read (perm-stored botL)
#pragma unroll
    for (int kc = 0; kc < 2; kc++) {
      bf16x8 paA = pack8(sA[2 * kc], sA[2 * kc + 1]);
      bf16x8 paB = pack8(sB[2 * kc], sB[2 * kc + 1]);
#pragma unroll
      for (int ct = 0; ct < 4; ct++) {
        bf16x8 bv = *(const bf16x8*)&botL[cur][(ct * 16 + col) * 64 + ((kc * 32 + kg * 8) ^ swc)];
        accOA[ct] = MFMA16(paA, bv, accOA[ct]);
        accOB[ct] = MFMA16(paB, bv, accOB[ct]);
      }
    }
    __syncthreads();
  }
  // raw bf16 partials: part[b][mc][n][c]  (invZ applied in k_xt1)
  unsigned short* po = part + (((size_t)(b * 8 + mc) * 4096 + nA) << 6);
#pragma unroll
  for (int ct = 0; ct < 4; ct++)
#pragma unroll
    for (int r = 0; r < 4; r++) {
      po[(kg * 4 + r) * 64 + ct * 16 + col] = f2bf(accOA[ct][r]);
      po[(64 + kg * 4 + r) * 64 + ct * 16 + col] = f2bf(accOB[ct][r]);
    }
  // Z partial: wave reduce + block reduce
#pragma unroll
  for (int off = 32; off; off >>= 1) zs += __shfl_xor(zs, off);
  if (lane == 0) zred[w] = zs;
  __syncthreads();
  if (t == 0) Zpart[b * 256 + ntp * 8 + mc] = zred[0] + zred[1] + zred[2] + zred[3];
}

// ---------------- yT = bf16(x + (sum_mc part) * invZ), vectorized -------------------
__global__ void k_xt1(const float* __restrict__ x, const unsigned short* __restrict__ part,
                      const float* __restrict__ Zpart, unsigned short* __restrict__ xT) {
  __shared__ float tile[64][65];
  __shared__ float zr[4];
  int bx = blockIdx.x;
  int b = bx >> 6;
  int n0 = (bx & 63) << 6;
  int t = threadIdx.x;
  float zv = Zpart[b * 256 + t];
#pragma unroll
  for (int off = 32; off; off >>= 1) zv += __shfl_xor(zv, off);
  if ((t & 63) == 0) zr[t >> 6] = zv;
  __syncthreads();
  float invZ = 1.0f / (zr[0] + zr[1] + zr[2] + zr[3]);
  {
    int c = t >> 2, nl16 = (t & 3) << 4;
    int nt6 = n0 >> 6;
    float acc[16];
#pragma unroll
    for (int k = 0; k < 16; k++) acc[k] = 0.f;
#pragma unroll
    for (int mcq = 0; mcq < 8; mcq++) {
      const unsigned short* pp =
          part + (((size_t)(b * 8 + mcq) * 4096) + c * 64 + nt6) * 64 + nl16;
      bf16x8 v0 = *(const bf16x8*)pp;
      bf16x8 v1 = *(const bf16x8*)(pp + 8);
#pragma unroll
      for (int k = 0; k < 8; k++) {
        acc[k] += bf2f((unsigned short)v0[k]);
        acc[8 + k] += bf2f((unsigned short)v1[k]);
      }
    }
    const float* xb = x + (size_t)b * 262144 + (size_t)c * 4096 + n0 + nl16;
#pragma unroll
    for (int q = 0; q < 4; q++) {
      f32x4 xv = *(const f32x4*)(xb + q * 4);
#pragma unroll
      for (int k = 0; k < 4; k++) tile[c][nl16 + q * 4 + k] = xv[k] + acc[q * 4 + k] * invZ;
    }
  }
  __syncthreads();
  {
    int n = t >> 2, c0 = (t & 3) << 4;
    bf16x8 o0, o1;
#pragma unroll
    for (int j = 0; j < 8; j++) {
      o0[j] = (short)f2bf(tile[c0 + j][n]);
      o1[j] = (short)f2bf(tile[c0 + 8 + j][n]);
    }
    unsigned short* dst = xT + ((size_t)(b * 4096 + n0 + n)) * 64 + c0;
    *(bf16x8*)(dst) = o0;
    *(bf16x8*)(dst + 8) = o1;
  }
}

// ---------------- host ----------------
extern "C" void kernel_launch(void* const* d_in, const int* in_sizes, int n_in,
                              void* d_out, int out_size, void* d_ws, size_t ws_size,
                              hipStream_t stream) {
  const float* x = (const float*)d_in[0];
  const float* tw = (const float*)d_in[1];
  const float* tb = (const float*)d_in[2];
  const float* cw = (const float*)d_in[3];
  const float* cbb = (const float*)d_in[4];
  const float* bw = (const float*)d_in[5];
  const float* bb = (const float*)d_in[6];
  const float* ow = (const float*)d_in[7];
  const float* ob = (const float*)d_in[8];
  float* out = (float*)d_out;
  char* ws = (char*)d_ws;

  unsigned short* wkTopF = (unsigned short*)(ws + 0);       // 8 KB (frag layout)
  unsigned short* wkCenF = (unsigned short*)(ws + 8192);    // 8 KB
  unsigned short* wkBotF = (unsigned short*)(ws + 16384);   // 216 KB
  unsigned short* wkOutF = (unsigned short*)(ws + 237568);  // 216 KB
  unsigned short* xT = (unsigned short*)(ws + 458752);      // 1 MB
  unsigned short* topT = (unsigned short*)(ws + 1507328);   // 1 MB
  unsigned short* cenT = (unsigned short*)(ws + 2555904);   // 1 MB
  unsigned short* botS = (unsigned short*)(ws + 3604480);   // 1 MB (sigma-permuted m)
  unsigned short* yT = (unsigned short*)(ws + 4653056);     // 1 MB
  unsigned short* part = (unsigned short*)(ws + 5701632);   // 8 MB bf16 [2][8][4096][64]
  float* Zpart = (float*)(ws + 14090240);                   // 2 KB
  unsigned short* zbuf = (unsigned short*)(ws + 14092288);  // 128 B zeros

  k_prep<<<560, 256, 0, stream>>>(tw, cw, bw, ow, x, wkTopF, wkCenF, wkBotF, wkOutF, xT, zbuf);
  k_convA<<<1024, 256, 0, stream>>>(wkTopF, wkCenF, wkBotF, xT, tb, cbb, bb, zbuf, topT, cenT, botS);
  k_pass2<<<512, 256, 0, stream>>>(cenT, topT, botS, part, Zpart);
  k_xt1<<<128, 256, 0, stream>>>(x, part, Zpart, yT);
  k_convOut<<<512, 256, 0, stream>>>(wkOutF, yT, ob, zbuf, out);
}